// Round 1
// baseline (1749.807 us; speedup 1.0000x reference)
//
#include <hip/hip_runtime.h>
#include <cmath>

#define C 128  // in/out channels

// ---------------------------------------------------------------------------
// Kernel 2: edge scatter — mean-aggregation numerator + degree counts.
// 32 lanes per edge; each lane handles 4 consecutive features (float4 gather,
// 4 scalar atomicAdds). lane 0 bumps the degree count.
// ---------------------------------------------------------------------------
__global__ __launch_bounds__(256)
void sage_scatter(const float* __restrict__ x, const int* __restrict__ ei,
                  float* __restrict__ summed, float* __restrict__ counts, int E) {
    int tid = blockIdx.x * blockDim.x + threadIdx.x;
    int e = tid >> 5;        // 32 lanes per edge
    int lane = tid & 31;
    if (e >= E) return;
    int src = ei[e];         // row 0 of edge_index
    int dst = ei[E + e];     // row 1 of edge_index
    const float4 v = *reinterpret_cast<const float4*>(x + (size_t)src * C + lane * 4);
    float* o = summed + (size_t)dst * C + lane * 4;
    atomicAdd(o + 0, v.x);
    atomicAdd(o + 1, v.y);
    atomicAdd(o + 2, v.z);
    atomicAdd(o + 3, v.w);
    if (lane == 0) atomicAdd(counts + dst, 1.0f);
}

// ---------------------------------------------------------------------------
// Kernel 3: fused  out = agg @ W_l^T + x @ W_r^T + b  -> log_softmax(axis=1)
// One 128-thread block (2 waves) per node. x-row and agg-row staged in LDS;
// thread j computes output feature j via two float4 dot products.
// ---------------------------------------------------------------------------
__global__ __launch_bounds__(128)
void sage_gemm_lsm(const float* __restrict__ x, const float* __restrict__ summed,
                   const float* __restrict__ counts,
                   const float* __restrict__ Wl, const float* __restrict__ Wr,
                   const float* __restrict__ b, float* __restrict__ out, int N) {
    int n = blockIdx.x;
    if (n >= N) return;
    int j = threadIdx.x;  // 0..127 : output feature

    __shared__ float sx[C];
    __shared__ float sa[C];
    __shared__ float red[4];

    float inv = 1.0f / fmaxf(counts[n], 1.0f);
    sx[j] = x[(size_t)n * C + j];
    sa[j] = summed[(size_t)n * C + j] * inv;
    __syncthreads();

    const float* wl = Wl + (size_t)j * C;
    const float* wr = Wr + (size_t)j * C;
    float acc = b[j];
#pragma unroll
    for (int k = 0; k < C; k += 4) {
        float4 a4 = *reinterpret_cast<const float4*>(wl + k);
        float4 b4 = *reinterpret_cast<const float4*>(wr + k);
        acc += a4.x * sa[k] + a4.y * sa[k + 1] + a4.z * sa[k + 2] + a4.w * sa[k + 3];
        acc += b4.x * sx[k] + b4.y * sx[k + 1] + b4.z * sx[k + 2] + b4.w * sx[k + 3];
    }

    // --- log_softmax over the 128 features (2 waves) ---
    int wave = j >> 6;
    float m = acc;
#pragma unroll
    for (int off = 1; off < 64; off <<= 1) m = fmaxf(m, __shfl_xor(m, off));
    if ((j & 63) == 0) red[wave] = m;
    __syncthreads();
    m = fmaxf(red[0], red[1]);

    float ex = expf(acc - m);
    float s = ex;
#pragma unroll
    for (int off = 1; off < 64; off <<= 1) s += __shfl_xor(s, off);
    if ((j & 63) == 0) red[2 + wave] = s;
    __syncthreads();
    s = red[2] + red[3];

    out[(size_t)n * C + j] = acc - m - logf(s);
}

extern "C" void kernel_launch(void* const* d_in, const int* in_sizes, int n_in,
                              void* d_out, int out_size, void* d_ws, size_t ws_size,
                              hipStream_t stream) {
    const float* x  = (const float*)d_in[0];
    const int*   ei = (const int*)d_in[1];
    const float* Wl = (const float*)d_in[2];
    const float* Wr = (const float*)d_in[3];
    const float* b  = (const float*)d_in[4];
    float* out = (float*)d_out;

    const int N = in_sizes[0] / C;       // 50000
    const int E = in_sizes[1] / 2;       // 600000

    float* summed = (float*)d_ws;                    // N*C floats
    float* counts = summed + (size_t)N * C;          // N floats
    size_t zero_bytes = ((size_t)N * C + N) * sizeof(float);

    hipMemsetAsync(d_ws, 0, zero_bytes, stream);

    {
        int threads = 256;
        long long total = (long long)E * 32;
        int blocks = (int)((total + threads - 1) / threads);
        sage_scatter<<<blocks, threads, 0, stream>>>(x, ei, summed, counts, E);
    }
    {
        sage_gemm_lsm<<<N, 128, 0, stream>>>(x, summed, counts, Wl, Wr, b, out, N);
    }
}

// Round 2
// 374.797 us; speedup vs baseline: 4.6687x; 4.6687x over previous
//
#include <hip/hip_runtime.h>
#include <cmath>

#define C 128     // in/out channels
#define NPB 32    // nodes per block in the fused kernel

// ---------------------------------------------------------------------------
// CSR build, step 1: in-degree counts (int atomics — cheap).
// ---------------------------------------------------------------------------
__global__ __launch_bounds__(256)
void sage_count(const int* __restrict__ ei, int* __restrict__ counts, int E) {
    int e = blockIdx.x * blockDim.x + threadIdx.x;
    if (e < E) atomicAdd(&counts[ei[E + e]], 1);
}

// ---------------------------------------------------------------------------
// CSR build, step 2: single-block exclusive scan of counts -> offs, cursor.
// 1024 threads, each owns a contiguous chunk; Hillis-Steele over chunk sums.
// ---------------------------------------------------------------------------
__global__ __launch_bounds__(1024)
void sage_scan(const int* __restrict__ counts, int* __restrict__ offs,
               int* __restrict__ cursor, int N) {
    __shared__ int part[1024];
    int t = threadIdx.x;
    int CHUNK = (N + 1023) >> 10;
    int lo = t * CHUNK, hi = min(lo + CHUNK, N);
    int s = 0;
    for (int i = lo; i < hi; ++i) s += counts[i];
    part[t] = s;
    __syncthreads();
    for (int off = 1; off < 1024; off <<= 1) {
        int v = (t >= off) ? part[t - off] : 0;
        __syncthreads();
        part[t] += v;
        __syncthreads();
    }
    int run = (t == 0) ? 0 : part[t - 1];
    for (int i = lo; i < hi; ++i) {
        offs[i] = run;
        cursor[i] = run;
        run += counts[i];
    }
    if (t == 1023) offs[N] = part[1023];
}

// ---------------------------------------------------------------------------
// CSR build, step 3: scatter src ids into neighbor lists.
// ---------------------------------------------------------------------------
__global__ __launch_bounds__(256)
void sage_fill(const int* __restrict__ ei, int* __restrict__ cursor,
               int* __restrict__ csr, int E) {
    int e = blockIdx.x * blockDim.x + threadIdx.x;
    if (e >= E) return;
    int src = ei[e];
    int pos = atomicAdd(&cursor[ei[E + e]], 1);
    csr[pos] = src;
}

// ---------------------------------------------------------------------------
// Fused: mean-aggregate (gather) + out = agg@Wl^T + x@Wr^T + b + log_softmax.
// Block = 256 threads = 4 waves, NPB=32 nodes.
//   Phase A: stage x rows (contiguous, coalesced).
//   Phase B: wave-per-node neighbor gather -> sa[] (no atomics).
//   Phase C: thread owns 2 features x 8 nodes; sa/sx reads are wave-uniform
//            broadcasts; W read from L2.
//   Phase D: log_softmax per node entirely within one wave (shfl_xor).
// ---------------------------------------------------------------------------
__global__ __launch_bounds__(256)
void sage_fused(const float* __restrict__ x, const int* __restrict__ offs,
                const int* __restrict__ csr,
                const float* __restrict__ Wl, const float* __restrict__ Wr,
                const float* __restrict__ bias,
                float* __restrict__ out, int N) {
    __shared__ float sx[NPB][C];   // 16 KB
    __shared__ float sa[NPB][C];   // 16 KB

    int t = threadIdx.x;
    int base = blockIdx.x * NPB;

    // ---- Phase A: stage x rows ----
    {
        const float4* x4 = (const float4*)(x + (size_t)base * C);
        float4* sx4 = (float4*)&sx[0][0];
#pragma unroll
        for (int j = 0; j < 4; ++j) {
            int idx = j * 256 + t;
            int node = idx >> 5;            // C/4 = 32 float4 per row
            float4 v = make_float4(0.f, 0.f, 0.f, 0.f);
            if (base + node < N) v = x4[idx];
            sx4[idx] = v;
        }
    }

    // ---- Phase B: mean aggregation, wave per node, lane = 2 features ----
    {
        int wv = t >> 6, ln = t & 63;
        for (int m = wv; m < NPB; m += 4) {
            int node = base + m;
            float ax = 0.f, ay = 0.f;
            if (node < N) {
                int p0 = offs[node], p1 = offs[node + 1];
#pragma unroll 2
                for (int p = p0; p < p1; ++p) {
                    int s = csr[p];
                    const float2 v = *(const float2*)(x + (size_t)s * C + ln * 2);
                    ax += v.x;
                    ay += v.y;
                }
                float inv = 1.0f / fmaxf((float)(p1 - p0), 1.0f);
                ax *= inv;
                ay *= inv;
            }
            float2 o;
            o.x = ax; o.y = ay;
            *(float2*)&sa[m][ln * 2] = o;
        }
    }
    __syncthreads();

    // ---- Phase C: GEMM, thread = 2 features x 8 nodes ----
    int fp = t & 63;        // feature pair index
    int ng = t >> 6;        // node group == wave id
    int f0 = fp * 2;
    const float4* wla = (const float4*)(Wl + (size_t)f0 * C);
    const float4* wlb = (const float4*)(Wl + (size_t)(f0 + 1) * C);
    const float4* wra = (const float4*)(Wr + (size_t)f0 * C);
    const float4* wrb = (const float4*)(Wr + (size_t)(f0 + 1) * C);
    float2 bz = *(const float2*)(bias + f0);
    float accA[8], accB[8];
#pragma unroll
    for (int i = 0; i < 8; ++i) { accA[i] = bz.x; accB[i] = bz.y; }

    for (int k4 = 0; k4 < C / 4; ++k4) {
        float4 la = wla[k4], lb = wlb[k4];
        float4 ra = wra[k4], rb = wrb[k4];
#pragma unroll
        for (int i = 0; i < 8; ++i) {
            int m = ng * 8 + i;
            float4 av = *(const float4*)&sa[m][k4 * 4];
            float4 xv = *(const float4*)&sx[m][k4 * 4];
            accA[i] += la.x * av.x + la.y * av.y + la.z * av.z + la.w * av.w
                     + ra.x * xv.x + ra.y * xv.y + ra.z * xv.z + ra.w * xv.w;
            accB[i] += lb.x * av.x + lb.y * av.y + lb.z * av.z + lb.w * av.w
                     + rb.x * xv.x + rb.y * xv.y + rb.z * xv.z + rb.w * xv.w;
        }
    }

    // ---- Phase D: log_softmax per node, whole node lives in this wave ----
#pragma unroll
    for (int i = 0; i < 8; ++i) {
        int node = base + ng * 8 + i;
        float m = fmaxf(accA[i], accB[i]);
#pragma unroll
        for (int off = 1; off < 64; off <<= 1)
            m = fmaxf(m, __shfl_xor(m, off));
        float s = expf(accA[i] - m) + expf(accB[i] - m);
#pragma unroll
        for (int off = 1; off < 64; off <<= 1)
            s += __shfl_xor(s, off);
        float ls = logf(s);
        if (node < N) {
            float2 o;
            o.x = accA[i] - m - ls;
            o.y = accB[i] - m - ls;
            *(float2*)(out + (size_t)node * C + f0) = o;
        }
    }
}

extern "C" void kernel_launch(void* const* d_in, const int* in_sizes, int n_in,
                              void* d_out, int out_size, void* d_ws, size_t ws_size,
                              hipStream_t stream) {
    const float* x  = (const float*)d_in[0];
    const int*   ei = (const int*)d_in[1];
    const float* Wl = (const float*)d_in[2];
    const float* Wr = (const float*)d_in[3];
    const float* b  = (const float*)d_in[4];
    float* out = (float*)d_out;

    const int N = in_sizes[0] / C;   // 50000
    const int E = in_sizes[1] / 2;   // 600000

    int* counts = (int*)d_ws;            // N
    int* offs   = counts + N;            // N+1
    int* cursor = offs + N + 1;          // N
    int* csr    = cursor + N;            // E

    hipMemsetAsync(counts, 0, (size_t)N * sizeof(int), stream);

    int eb = (E + 255) / 256;
    sage_count<<<eb, 256, 0, stream>>>(ei, counts, E);
    sage_scan<<<1, 1024, 0, stream>>>(counts, offs, cursor, N);
    sage_fill<<<eb, 256, 0, stream>>>(ei, cursor, csr, E);
    sage_fused<<<(N + NPB - 1) / NPB, 256, 0, stream>>>(x, offs, csr, Wl, Wr, b, out, N);
}

// Round 3
// 273.355 us; speedup vs baseline: 6.4012x; 1.3711x over previous
//
#include <hip/hip_runtime.h>
#include <cmath>

#define C 128     // in/out channels
#define NPB 32    // nodes per block in the fused kernel

// ---------------------------------------------------------------------------
// CSR build, step 1: in-degree counts (int atomics), 4 edges/thread.
// ---------------------------------------------------------------------------
__global__ __launch_bounds__(256)
void sage_count(const int* __restrict__ ei, int* __restrict__ counts, int E) {
    int i = blockIdx.x * blockDim.x + threadIdx.x;
    int e = i * 4;
    if (e + 3 < E) {
        int4 d = *(const int4*)(ei + E + e);
        atomicAdd(&counts[d.x], 1);
        atomicAdd(&counts[d.y], 1);
        atomicAdd(&counts[d.z], 1);
        atomicAdd(&counts[d.w], 1);
    } else {
        for (; e < E; ++e) atomicAdd(&counts[ei[E + e]], 1);
    }
}

// ---------------------------------------------------------------------------
// CSR build, step 2: single-block exclusive scan (1024 thr, 64 ints each,
// int4-vectorized) -> offs, cursor.
// ---------------------------------------------------------------------------
__global__ __launch_bounds__(1024)
void sage_scan(const int* __restrict__ counts, int* __restrict__ offs,
               int* __restrict__ cursor, int N) {
    __shared__ int part[1024];
    const int t = threadIdx.x;
    const int CH = 64;                    // 1024 * 64 = 65536 >= N
    const int lo = t * CH;

    int s = 0;
    if (lo + CH <= N) {
        const int4* c4 = (const int4*)(counts + lo);
#pragma unroll
        for (int i = 0; i < CH / 4; ++i) {
            int4 v = c4[i];
            s += v.x + v.y + v.z + v.w;
        }
    } else {
        for (int i = lo; i < N; ++i) s += counts[i];
    }
    part[t] = s;
    __syncthreads();
    for (int off = 1; off < 1024; off <<= 1) {
        int v = (t >= off) ? part[t - off] : 0;
        __syncthreads();
        part[t] += v;
        __syncthreads();
    }
    int run = (t == 0) ? 0 : part[t - 1];

    if (lo + CH <= N) {
        const int4* c4 = (const int4*)(counts + lo);
        int4* o4 = (int4*)(offs + lo);
        int4* u4 = (int4*)(cursor + lo);
#pragma unroll
        for (int i = 0; i < CH / 4; ++i) {
            int4 v = c4[i];
            int4 o;
            o.x = run; run += v.x;
            o.y = run; run += v.y;
            o.z = run; run += v.z;
            o.w = run; run += v.w;
            o4[i] = o;
            u4[i] = o;
        }
    } else {
        for (int i = lo; i < N; ++i) {
            offs[i] = run;
            cursor[i] = run;
            run += counts[i];
        }
    }
    if (t == 1023) offs[N] = part[1023];
}

// ---------------------------------------------------------------------------
// CSR build, step 3: scatter src ids into neighbor lists, 4 edges/thread.
// ---------------------------------------------------------------------------
__global__ __launch_bounds__(256)
void sage_fill(const int* __restrict__ ei, int* __restrict__ cursor,
               int* __restrict__ csr, int E) {
    int i = blockIdx.x * blockDim.x + threadIdx.x;
    int e = i * 4;
    if (e + 3 < E) {
        int4 sv = *(const int4*)(ei + e);
        int4 dv = *(const int4*)(ei + E + e);
        csr[atomicAdd(&cursor[dv.x], 1)] = sv.x;
        csr[atomicAdd(&cursor[dv.y], 1)] = sv.y;
        csr[atomicAdd(&cursor[dv.z], 1)] = sv.z;
        csr[atomicAdd(&cursor[dv.w], 1)] = sv.w;
    } else {
        for (; e < E; ++e) {
            int pos = atomicAdd(&cursor[ei[E + e]], 1);
            csr[pos] = ei[e];
        }
    }
}

// ---------------------------------------------------------------------------
// Fused: mean-aggregate (gather) + out = agg@Wl^T + x@Wr^T + b + log_softmax.
// Block = 256 threads = 4 waves, NPB=32 nodes.
//   Phase B now: float4/lane, half-waves own alternate neighbors (2 full rows
//   per wave-load), manual 2x unroll => 4 rows in flight per wave.
// ---------------------------------------------------------------------------
__global__ __launch_bounds__(256)
void sage_fused(const float* __restrict__ x, const int* __restrict__ offs,
                const int* __restrict__ csr,
                const float* __restrict__ Wl, const float* __restrict__ Wr,
                const float* __restrict__ bias,
                float* __restrict__ out, int N) {
    __shared__ float sx[NPB][C];   // 16 KB
    __shared__ float sa[NPB][C];   // 16 KB

    int t = threadIdx.x;
    int base = blockIdx.x * NPB;

    // ---- Phase A: stage x rows (coalesced) ----
    {
        const float4* x4 = (const float4*)(x + (size_t)base * C);
        float4* sx4 = (float4*)&sx[0][0];
#pragma unroll
        for (int j = 0; j < 4; ++j) {
            int idx = j * 256 + t;
            int node = idx >> 5;            // C/4 = 32 float4 per row
            float4 v = make_float4(0.f, 0.f, 0.f, 0.f);
            if (base + node < N) v = x4[idx];
            sx4[idx] = v;
        }
    }

    // ---- Phase B: mean aggregation, wave per node, 4 rows in flight ----
    {
        int wv = t >> 6, ln = t & 63;
        int half = ln >> 5;     // half-wave id: owns alternate neighbors
        int fl = ln & 31;       // float4 index within the row
        for (int m = wv; m < NPB; m += 4) {
            int node = base + m;
            float4 a0 = make_float4(0.f, 0.f, 0.f, 0.f);
            float4 a1 = make_float4(0.f, 0.f, 0.f, 0.f);
            float inv = 0.f;
            if (node < N) {
                int p0 = offs[node], p1 = offs[node + 1];
                int p = p0 + half;
                for (; p + 2 < p1; p += 4) {
                    int s0 = csr[p];
                    int s1 = csr[p + 2];
                    const float4 v0 = *(const float4*)(x + (size_t)s0 * C + fl * 4);
                    const float4 v1 = *(const float4*)(x + (size_t)s1 * C + fl * 4);
                    a0.x += v0.x; a0.y += v0.y; a0.z += v0.z; a0.w += v0.w;
                    a1.x += v1.x; a1.y += v1.y; a1.z += v1.z; a1.w += v1.w;
                }
                if (p < p1) {
                    int s0 = csr[p];
                    const float4 v0 = *(const float4*)(x + (size_t)s0 * C + fl * 4);
                    a0.x += v0.x; a0.y += v0.y; a0.z += v0.z; a0.w += v0.w;
                }
                inv = 1.0f / fmaxf((float)(p1 - p0), 1.0f);
            }
            float4 r;
            r.x = a0.x + a1.x; r.y = a0.y + a1.y;
            r.z = a0.z + a1.z; r.w = a0.w + a1.w;
            r.x += __shfl_xor(r.x, 32);
            r.y += __shfl_xor(r.y, 32);
            r.z += __shfl_xor(r.z, 32);
            r.w += __shfl_xor(r.w, 32);
            if (half == 0) {
                r.x *= inv; r.y *= inv; r.z *= inv; r.w *= inv;
                *(float4*)&sa[m][fl * 4] = r;
            }
        }
    }
    __syncthreads();

    // ---- Phase C: GEMM, thread = 2 features x 8 nodes ----
    int fp = t & 63;        // feature pair index
    int ng = t >> 6;        // node group == wave id
    int f0 = fp * 2;
    const float4* wla = (const float4*)(Wl + (size_t)f0 * C);
    const float4* wlb = (const float4*)(Wl + (size_t)(f0 + 1) * C);
    const float4* wra = (const float4*)(Wr + (size_t)f0 * C);
    const float4* wrb = (const float4*)(Wr + (size_t)(f0 + 1) * C);
    float2 bz = *(const float2*)(bias + f0);
    float accA[8], accB[8];
#pragma unroll
    for (int i = 0; i < 8; ++i) { accA[i] = bz.x; accB[i] = bz.y; }

    for (int k4 = 0; k4 < C / 4; ++k4) {
        float4 la = wla[k4], lb = wlb[k4];
        float4 ra = wra[k4], rb = wrb[k4];
#pragma unroll
        for (int i = 0; i < 8; ++i) {
            int m = ng * 8 + i;
            float4 av = *(const float4*)&sa[m][k4 * 4];
            float4 xv = *(const float4*)&sx[m][k4 * 4];
            accA[i] += la.x * av.x + la.y * av.y + la.z * av.z + la.w * av.w
                     + ra.x * xv.x + ra.y * xv.y + ra.z * xv.z + ra.w * xv.w;
            accB[i] += lb.x * av.x + lb.y * av.y + lb.z * av.z + lb.w * av.w
                     + rb.x * xv.x + rb.y * xv.y + rb.z * xv.z + rb.w * xv.w;
        }
    }

    // ---- Phase D: log_softmax per node (whole node within one wave) ----
#pragma unroll
    for (int i = 0; i < 8; ++i) {
        int node = base + ng * 8 + i;
        float m = fmaxf(accA[i], accB[i]);
#pragma unroll
        for (int off = 1; off < 64; off <<= 1)
            m = fmaxf(m, __shfl_xor(m, off));
        float s = expf(accA[i] - m) + expf(accB[i] - m);
#pragma unroll
        for (int off = 1; off < 64; off <<= 1)
            s += __shfl_xor(s, off);
        float ls = logf(s);
        if (node < N) {
            float2 o;
            o.x = accA[i] - m - ls;
            o.y = accB[i] - m - ls;
            *(float2*)(out + (size_t)node * C + f0) = o;
        }
    }
}

extern "C" void kernel_launch(void* const* d_in, const int* in_sizes, int n_in,
                              void* d_out, int out_size, void* d_ws, size_t ws_size,
                              hipStream_t stream) {
    const float* x  = (const float*)d_in[0];
    const int*   ei = (const int*)d_in[1];
    const float* Wl = (const float*)d_in[2];
    const float* Wr = (const float*)d_in[3];
    const float* b  = (const float*)d_in[4];
    float* out = (float*)d_out;

    const int N = in_sizes[0] / C;   // 50000
    const int E = in_sizes[1] / 2;   // 600000

    // ws layout (ints), all 16B-aligned:
    int* counts = (int*)d_ws;                    // N
    int* offs   = counts + N;                    // N+1 (padded to N+4)
    int* cursor = offs + ((N + 4) & ~3);         // N
    int* csr    = cursor + N;                    // E

    hipMemsetAsync(counts, 0, (size_t)N * sizeof(int), stream);

    int eb4 = (E + 1023) / 1024;
    sage_count<<<eb4, 256, 0, stream>>>(ei, counts, E);
    sage_scan<<<1, 1024, 0, stream>>>(counts, offs, cursor, N);
    sage_fill<<<eb4, 256, 0, stream>>>(ei, cursor, csr, E);
    sage_fused<<<(N + NPB - 1) / NPB, 256, 0, stream>>>(x, offs, csr, Wl, Wr, b, out, N);
}

// Round 4
// 258.834 us; speedup vs baseline: 6.7603x; 1.0561x over previous
//
#include <hip/hip_runtime.h>
#include <cmath>

#define C 128     // in/out channels
#define NPB 32    // nodes per block in the GEMM kernel

// ---------------------------------------------------------------------------
// CSR build, step 1: in-degree counts (int atomics), 4 edges/thread.
// ---------------------------------------------------------------------------
__global__ __launch_bounds__(256)
void sage_count(const int* __restrict__ ei, int* __restrict__ counts, int E) {
    int i = blockIdx.x * blockDim.x + threadIdx.x;
    int e = i * 4;
    if (e + 3 < E) {
        int4 d = *(const int4*)(ei + E + e);
        atomicAdd(&counts[d.x], 1);
        atomicAdd(&counts[d.y], 1);
        atomicAdd(&counts[d.z], 1);
        atomicAdd(&counts[d.w], 1);
    } else {
        for (; e < E; ++e) atomicAdd(&counts[ei[E + e]], 1);
    }
}

// ---------------------------------------------------------------------------
// CSR build, step 2: single-block exclusive scan (1024 thr, int4-vectorized).
// ---------------------------------------------------------------------------
__global__ __launch_bounds__(1024)
void sage_scan(const int* __restrict__ counts, int* __restrict__ offs,
               int* __restrict__ cursor, int N) {
    __shared__ int part[1024];
    const int t = threadIdx.x;
    const int CH = 64;                    // 1024 * 64 = 65536 >= N
    const int lo = t * CH;

    int s = 0;
    if (lo + CH <= N) {
        const int4* c4 = (const int4*)(counts + lo);
#pragma unroll
        for (int i = 0; i < CH / 4; ++i) {
            int4 v = c4[i];
            s += v.x + v.y + v.z + v.w;
        }
    } else {
        for (int i = lo; i < N; ++i) s += counts[i];
    }
    part[t] = s;
    __syncthreads();
    for (int off = 1; off < 1024; off <<= 1) {
        int v = (t >= off) ? part[t - off] : 0;
        __syncthreads();
        part[t] += v;
        __syncthreads();
    }
    int run = (t == 0) ? 0 : part[t - 1];

    if (lo + CH <= N) {
        const int4* c4 = (const int4*)(counts + lo);
        int4* o4 = (int4*)(offs + lo);
        int4* u4 = (int4*)(cursor + lo);
#pragma unroll
        for (int i = 0; i < CH / 4; ++i) {
            int4 v = c4[i];
            int4 o;
            o.x = run; run += v.x;
            o.y = run; run += v.y;
            o.z = run; run += v.z;
            o.w = run; run += v.w;
            o4[i] = o;
            u4[i] = o;
        }
    } else {
        for (int i = lo; i < N; ++i) {
            offs[i] = run;
            cursor[i] = run;
            run += counts[i];
        }
    }
    if (t == 1023) offs[N] = part[1023];
}

// ---------------------------------------------------------------------------
// CSR build, step 3: scatter src ids into neighbor lists, 4 edges/thread.
// ---------------------------------------------------------------------------
__global__ __launch_bounds__(256)
void sage_fill(const int* __restrict__ ei, int* __restrict__ cursor,
               int* __restrict__ csr, int E) {
    int i = blockIdx.x * blockDim.x + threadIdx.x;
    int e = i * 4;
    if (e + 3 < E) {
        int4 sv = *(const int4*)(ei + e);
        int4 dv = *(const int4*)(ei + E + e);
        csr[atomicAdd(&cursor[dv.x], 1)] = sv.x;
        csr[atomicAdd(&cursor[dv.y], 1)] = sv.y;
        csr[atomicAdd(&cursor[dv.z], 1)] = sv.z;
        csr[atomicAdd(&cursor[dv.w], 1)] = sv.w;
    } else {
        for (; e < E; ++e) {
            int pos = atomicAdd(&cursor[ei[E + e]], 1);
            csr[pos] = ei[e];
        }
    }
}

// ---------------------------------------------------------------------------
// Aggregation: one wave per node, NO LDS -> high occupancy hides gather
// latency. Half-waves own alternate neighbors (residues {h, h+2} mod 4),
// 4 rows in flight per half-wave, combined by shfl_xor(32). Writes the
// mean row to agg[].
// ---------------------------------------------------------------------------
__global__ __launch_bounds__(256)
void sage_agg(const float* __restrict__ x, const int* __restrict__ offs,
              const int* __restrict__ csr, float* __restrict__ agg, int N) {
    int wv = threadIdx.x >> 6;
    int node = blockIdx.x * 4 + wv;
    if (node >= N) return;
    int ln = threadIdx.x & 63;
    int half = ln >> 5;     // half-wave id
    int fl = ln & 31;       // float4 index within the row

    int p0 = offs[node], p1 = offs[node + 1];
    float4 a0 = make_float4(0.f, 0.f, 0.f, 0.f);
    float4 a1 = make_float4(0.f, 0.f, 0.f, 0.f);
    int p = p0 + half;
    for (; p + 6 < p1; p += 8) {
        int s0 = csr[p];
        int s1 = csr[p + 2];
        int s2 = csr[p + 4];
        int s3 = csr[p + 6];
        float4 v0 = *(const float4*)(x + (size_t)s0 * C + fl * 4);
        float4 v1 = *(const float4*)(x + (size_t)s1 * C + fl * 4);
        float4 v2 = *(const float4*)(x + (size_t)s2 * C + fl * 4);
        float4 v3 = *(const float4*)(x + (size_t)s3 * C + fl * 4);
        a0.x += v0.x; a0.y += v0.y; a0.z += v0.z; a0.w += v0.w;
        a1.x += v1.x; a1.y += v1.y; a1.z += v1.z; a1.w += v1.w;
        a0.x += v2.x; a0.y += v2.y; a0.z += v2.z; a0.w += v2.w;
        a1.x += v3.x; a1.y += v3.y; a1.z += v3.z; a1.w += v3.w;
    }
    for (; p < p1; p += 2) {
        int s0 = csr[p];
        float4 v0 = *(const float4*)(x + (size_t)s0 * C + fl * 4);
        a0.x += v0.x; a0.y += v0.y; a0.z += v0.z; a0.w += v0.w;
    }
    float4 r;
    r.x = a0.x + a1.x; r.y = a0.y + a1.y;
    r.z = a0.z + a1.z; r.w = a0.w + a1.w;
    r.x += __shfl_xor(r.x, 32);
    r.y += __shfl_xor(r.y, 32);
    r.z += __shfl_xor(r.z, 32);
    r.w += __shfl_xor(r.w, 32);
    if (half == 0) {
        float inv = 1.0f / fmaxf((float)(p1 - p0), 1.0f);
        r.x *= inv; r.y *= inv; r.z *= inv; r.w *= inv;
        *(float4*)(agg + (size_t)node * C + fl * 4) = r;
    }
}

// ---------------------------------------------------------------------------
// GEMM + log_softmax: out = agg@Wl^T + x@Wr^T + b -> log_softmax.
// Block = 256 threads = 4 waves, NPB=32 nodes; x/agg rows staged in LDS
// (coalesced), thread owns 2 features x 8 nodes, per-node softmax within
// one wave via shfl.
// ---------------------------------------------------------------------------
__global__ __launch_bounds__(256)
void sage_gemm_lsm(const float* __restrict__ x, const float* __restrict__ agg,
                   const float* __restrict__ Wl, const float* __restrict__ Wr,
                   const float* __restrict__ bias,
                   float* __restrict__ out, int N) {
    __shared__ float sx[NPB][C];   // 16 KB
    __shared__ float sa[NPB][C];   // 16 KB

    int t = threadIdx.x;
    int base = blockIdx.x * NPB;

    // ---- stage x and agg rows (coalesced) ----
    {
        const float4* x4 = (const float4*)(x + (size_t)base * C);
        const float4* a4 = (const float4*)(agg + (size_t)base * C);
        float4* sx4 = (float4*)&sx[0][0];
        float4* sa4 = (float4*)&sa[0][0];
#pragma unroll
        for (int j = 0; j < 4; ++j) {
            int idx = j * 256 + t;
            int node = idx >> 5;            // C/4 = 32 float4 per row
            float4 vx = make_float4(0.f, 0.f, 0.f, 0.f);
            float4 va = make_float4(0.f, 0.f, 0.f, 0.f);
            if (base + node < N) { vx = x4[idx]; va = a4[idx]; }
            sx4[idx] = vx;
            sa4[idx] = va;
        }
    }
    __syncthreads();

    // ---- GEMM: thread = 2 features x 8 nodes ----
    int fp = t & 63;        // feature pair index
    int ng = t >> 6;        // node group == wave id
    int f0 = fp * 2;
    const float4* wla = (const float4*)(Wl + (size_t)f0 * C);
    const float4* wlb = (const float4*)(Wl + (size_t)(f0 + 1) * C);
    const float4* wra = (const float4*)(Wr + (size_t)f0 * C);
    const float4* wrb = (const float4*)(Wr + (size_t)(f0 + 1) * C);
    float2 bz = *(const float2*)(bias + f0);
    float accA[8], accB[8];
#pragma unroll
    for (int i = 0; i < 8; ++i) { accA[i] = bz.x; accB[i] = bz.y; }

    for (int k4 = 0; k4 < C / 4; ++k4) {
        float4 la = wla[k4], lb = wlb[k4];
        float4 ra = wra[k4], rb = wrb[k4];
#pragma unroll
        for (int i = 0; i < 8; ++i) {
            int m = ng * 8 + i;
            float4 av = *(const float4*)&sa[m][k4 * 4];
            float4 xv = *(const float4*)&sx[m][k4 * 4];
            accA[i] += la.x * av.x + la.y * av.y + la.z * av.z + la.w * av.w
                     + ra.x * xv.x + ra.y * xv.y + ra.z * xv.z + ra.w * xv.w;
            accB[i] += lb.x * av.x + lb.y * av.y + lb.z * av.z + lb.w * av.w
                     + rb.x * xv.x + rb.y * xv.y + rb.z * xv.z + rb.w * xv.w;
        }
    }

    // ---- log_softmax per node (whole node within one wave) ----
#pragma unroll
    for (int i = 0; i < 8; ++i) {
        int node = base + ng * 8 + i;
        float m = fmaxf(accA[i], accB[i]);
#pragma unroll
        for (int off = 1; off < 64; off <<= 1)
            m = fmaxf(m, __shfl_xor(m, off));
        float s = expf(accA[i] - m) + expf(accB[i] - m);
#pragma unroll
        for (int off = 1; off < 64; off <<= 1)
            s += __shfl_xor(s, off);
        float ls = logf(s);
        if (node < N) {
            float2 o;
            o.x = accA[i] - m - ls;
            o.y = accB[i] - m - ls;
            *(float2*)(out + (size_t)node * C + f0) = o;
        }
    }
}

extern "C" void kernel_launch(void* const* d_in, const int* in_sizes, int n_in,
                              void* d_out, int out_size, void* d_ws, size_t ws_size,
                              hipStream_t stream) {
    const float* x  = (const float*)d_in[0];
    const int*   ei = (const int*)d_in[1];
    const float* Wl = (const float*)d_in[2];
    const float* Wr = (const float*)d_in[3];
    const float* b  = (const float*)d_in[4];
    float* out = (float*)d_out;

    const int N = in_sizes[0] / C;   // 50000
    const int E = in_sizes[1] / 2;   // 600000

    // ws layout (all 16B-aligned)
    int* counts = (int*)d_ws;                        // N
    int* offs   = counts + ((N + 3) & ~3);           // N+1 (padded)
    int* cursor = offs + ((N + 7) & ~3);             // N
    int* csr    = cursor + ((N + 3) & ~3);           // E
    float* agg  = (float*)(csr + ((E + 3) & ~3));    // N*C

    hipMemsetAsync(counts, 0, (size_t)N * sizeof(int), stream);

    int eb4 = (E + 1023) / 1024;
    sage_count<<<eb4, 256, 0, stream>>>(ei, counts, E);
    sage_scan<<<1, 1024, 0, stream>>>(counts, offs, cursor, N);
    sage_fill<<<eb4, 256, 0, stream>>>(ei, cursor, csr, E);
    sage_agg<<<(N + 3) / 4, 256, 0, stream>>>(x, offs, csr, agg, N);
    sage_gemm_lsm<<<(N + NPB - 1) / NPB, 256, 0, stream>>>(x, agg, Wl, Wr, b, out, N);
}

// Round 5
// 165.284 us; speedup vs baseline: 10.5867x; 1.5660x over previous
//
#include <hip/hip_runtime.h>
#include <cmath>

#define C 128     // in/out channels

typedef __bf16 bf16x8 __attribute__((ext_vector_type(8)));
typedef float  f32x4  __attribute__((ext_vector_type(4)));

// fp32 -> bf16 bits, round-to-nearest-even
static __device__ __forceinline__ unsigned short f2b(float f) {
    unsigned int u = __builtin_bit_cast(unsigned int, f);
    u += 0x7FFFu + ((u >> 16) & 1u);
    return (unsigned short)(u >> 16);
}

// ---------------------------------------------------------------------------
// CSR build, step 1: in-degree counts (int atomics), 4 edges/thread.
// ---------------------------------------------------------------------------
__global__ __launch_bounds__(256)
void sage_count(const int* __restrict__ ei, int* __restrict__ counts, int E) {
    int i = blockIdx.x * blockDim.x + threadIdx.x;
    int e = i * 4;
    if (e + 3 < E) {
        int4 d = *(const int4*)(ei + E + e);
        atomicAdd(&counts[d.x], 1);
        atomicAdd(&counts[d.y], 1);
        atomicAdd(&counts[d.z], 1);
        atomicAdd(&counts[d.w], 1);
    } else {
        for (; e < E; ++e) atomicAdd(&counts[ei[E + e]], 1);
    }
}

// ---------------------------------------------------------------------------
// CSR build, step 2: single-block exclusive scan -> cursor (only).
// After sage_fill, cursor[i] == inclusive scan (end offset of node i).
// ---------------------------------------------------------------------------
__global__ __launch_bounds__(1024)
void sage_scan(const int* __restrict__ counts, int* __restrict__ cursor, int N) {
    __shared__ int part[1024];
    const int t = threadIdx.x;
    const int CH = 64;                    // 1024 * 64 = 65536 >= N
    const int lo = t * CH;

    int s = 0;
    if (lo + CH <= N) {
        const int4* c4 = (const int4*)(counts + lo);
#pragma unroll
        for (int i = 0; i < CH / 4; ++i) {
            int4 v = c4[i];
            s += v.x + v.y + v.z + v.w;
        }
    } else {
        for (int i = lo; i < N; ++i) s += counts[i];
    }
    part[t] = s;
    __syncthreads();
    for (int off = 1; off < 1024; off <<= 1) {
        int v = (t >= off) ? part[t - off] : 0;
        __syncthreads();
        part[t] += v;
        __syncthreads();
    }
    int run = (t == 0) ? 0 : part[t - 1];

    if (lo + CH <= N) {
        const int4* c4 = (const int4*)(counts + lo);
        int4* u4 = (int4*)(cursor + lo);
#pragma unroll
        for (int i = 0; i < CH / 4; ++i) {
            int4 v = c4[i];
            int4 o;
            o.x = run; run += v.x;
            o.y = run; run += v.y;
            o.z = run; run += v.z;
            o.w = run; run += v.w;
            u4[i] = o;
        }
    } else {
        for (int i = lo; i < N; ++i) {
            cursor[i] = run;
            run += counts[i];
        }
    }
}

// ---------------------------------------------------------------------------
// CSR build, step 3: scatter src ids; cursor becomes inclusive scan.
// ---------------------------------------------------------------------------
__global__ __launch_bounds__(256)
void sage_fill(const int* __restrict__ ei, int* __restrict__ cursor,
               int* __restrict__ csr, int E) {
    int i = blockIdx.x * blockDim.x + threadIdx.x;
    int e = i * 4;
    if (e + 3 < E) {
        int4 sv = *(const int4*)(ei + e);
        int4 dv = *(const int4*)(ei + E + e);
        csr[atomicAdd(&cursor[dv.x], 1)] = sv.x;
        csr[atomicAdd(&cursor[dv.y], 1)] = sv.y;
        csr[atomicAdd(&cursor[dv.z], 1)] = sv.z;
        csr[atomicAdd(&cursor[dv.w], 1)] = sv.w;
    } else {
        for (; e < E; ++e) {
            int pos = atomicAdd(&cursor[ei[E + e]], 1);
            csr[pos] = ei[e];
        }
    }
}

// ---------------------------------------------------------------------------
// Fused conversion kernel:
//  blocks [0, XB): x fp32 -> bf16 (4 elems/thread)
//  blocks [XB, XB+16): pack B = [Wl;Wr] (K=256 x N=128) into MFMA-fragment
//  order: frag f = t*8+c (t k-tile, c n-tile), lane l, elem j:
//    k = t*32 + (l>>4)*8 + j,  n = c*16 + (l&15)
//  Same k-slot convention as the A side => correct regardless of hw k-perm.
// ---------------------------------------------------------------------------
__global__ __launch_bounds__(256)
void sage_conv(const float* __restrict__ x, const float* __restrict__ Wl,
               const float* __restrict__ Wr, unsigned short* __restrict__ xb,
               unsigned short* __restrict__ wp, int XB) {
    int bid = blockIdx.x;
    if (bid < XB) {
        int i = bid * 256 + threadIdx.x;     // < N*C/4
        float4 v = ((const float4*)x)[i];
        ushort4 o;
        o.x = f2b(v.x); o.y = f2b(v.y); o.z = f2b(v.z); o.w = f2b(v.w);
        ((ushort4*)xb)[i] = o;
    } else {
        int s = (bid - XB) * 256 + threadIdx.x;   // 0..4095
        int f = s >> 6, l = s & 63;
        int t = f >> 3, c = f & 7;
        int g = l >> 4;
        int n = c * 16 + (l & 15);
        ushort4 lo, hi;
        unsigned short tmp[8];
#pragma unroll
        for (int j = 0; j < 8; ++j) {
            int k = t * 32 + g * 8 + j;
            float v = (k < C) ? Wl[(size_t)n * C + k] : Wr[(size_t)n * C + (k - C)];
            tmp[j] = f2b(v);
        }
        lo.x = tmp[0]; lo.y = tmp[1]; lo.z = tmp[2]; lo.w = tmp[3];
        hi.x = tmp[4]; hi.y = tmp[5]; hi.z = tmp[6]; hi.w = tmp[7];
        ((ushort4*)wp)[s * 2 + 0] = lo;
        ((ushort4*)wp)[s * 2 + 1] = hi;
    }
}

// ---------------------------------------------------------------------------
// Aggregation: one wave per node, no LDS (full occupancy hides gather
// latency). Writes the mean row directly as bf16.
// ---------------------------------------------------------------------------
__global__ __launch_bounds__(256)
void sage_agg(const float* __restrict__ x, const int* __restrict__ cursor,
              const int* __restrict__ csr, unsigned short* __restrict__ aggb,
              int N) {
    int wv = threadIdx.x >> 6;
    int node = blockIdx.x * 4 + wv;
    if (node >= N) return;
    int ln = threadIdx.x & 63;
    int half = ln >> 5;
    int fl = ln & 31;

    int p0 = (node == 0) ? 0 : cursor[node - 1];
    int p1 = cursor[node];
    float4 a0 = make_float4(0.f, 0.f, 0.f, 0.f);
    float4 a1 = make_float4(0.f, 0.f, 0.f, 0.f);
    int p = p0 + half;
    for (; p + 6 < p1; p += 8) {
        int s0 = csr[p];
        int s1 = csr[p + 2];
        int s2 = csr[p + 4];
        int s3 = csr[p + 6];
        float4 v0 = *(const float4*)(x + (size_t)s0 * C + fl * 4);
        float4 v1 = *(const float4*)(x + (size_t)s1 * C + fl * 4);
        float4 v2 = *(const float4*)(x + (size_t)s2 * C + fl * 4);
        float4 v3 = *(const float4*)(x + (size_t)s3 * C + fl * 4);
        a0.x += v0.x; a0.y += v0.y; a0.z += v0.z; a0.w += v0.w;
        a1.x += v1.x; a1.y += v1.y; a1.z += v1.z; a1.w += v1.w;
        a0.x += v2.x; a0.y += v2.y; a0.z += v2.z; a0.w += v2.w;
        a1.x += v3.x; a1.y += v3.y; a1.z += v3.z; a1.w += v3.w;
    }
    for (; p < p1; p += 2) {
        int s0 = csr[p];
        float4 v0 = *(const float4*)(x + (size_t)s0 * C + fl * 4);
        a0.x += v0.x; a0.y += v0.y; a0.z += v0.z; a0.w += v0.w;
    }
    float4 r;
    r.x = a0.x + a1.x; r.y = a0.y + a1.y;
    r.z = a0.z + a1.z; r.w = a0.w + a1.w;
    r.x += __shfl_xor(r.x, 32);
    r.y += __shfl_xor(r.y, 32);
    r.z += __shfl_xor(r.z, 32);
    r.w += __shfl_xor(r.w, 32);
    if (half == 0) {
        float inv = 1.0f / fmaxf((float)(p1 - p0), 1.0f);
        ushort4 o;
        o.x = f2b(r.x * inv);
        o.y = f2b(r.y * inv);
        o.z = f2b(r.z * inv);
        o.w = f2b(r.w * inv);
        *(ushort4*)(aggb + (size_t)node * C + fl * 4) = o;
    }
}

// ---------------------------------------------------------------------------
// MFMA GEMM + log_softmax. Block = 256 thr = 4 waves = 16 nodes x 128 feats.
// K = 256 ([agg | x]). Wave w owns n-tiles {2w, 2w+1}; 16 mfma/wave.
// A-frag (lane l): node = base + (l&15), k = t*32 + (l>>4)*8 + j  (16B load).
// B-frag: pre-packed wp, one coalesced 16B/lane load.
// D (verified m89): col(feat-in-tile) = l&15, row(node-in-tile) = (l>>4)*4+reg.
// Epilogue via 8.4 KB LDS; per-node softmax within one wave.
// ---------------------------------------------------------------------------
__global__ __launch_bounds__(256)
void sage_mfma_lsm(const unsigned short* __restrict__ xb,
                   const unsigned short* __restrict__ aggb,
                   const unsigned short* __restrict__ wp,
                   const float* __restrict__ bias,
                   float* __restrict__ out, int N) {
    __shared__ float so[16][132];   // +4 pad: 2-way-max bank aliasing on writes

    int t = threadIdx.x;
    int w = t >> 6, l = t & 63;
    int base = blockIdx.x * 16;
    int g = l >> 4;
    int node = base + (l & 15);

    const bf16x8* Aa = (const bf16x8*)(aggb + (size_t)node * C);
    const bf16x8* Ax = (const bf16x8*)(xb   + (size_t)node * C);
    const bf16x8* B  = (const bf16x8*)wp;

    int c0 = w * 2, c1 = w * 2 + 1;
    f32x4 acc0 = {0.f, 0.f, 0.f, 0.f};
    f32x4 acc1 = {0.f, 0.f, 0.f, 0.f};

#pragma unroll
    for (int t8 = 0; t8 < 8; ++t8) {
        bf16x8 a = (t8 < 4) ? Aa[t8 * 4 + g] : Ax[(t8 - 4) * 4 + g];
        bf16x8 b0 = B[(size_t)(t8 * 8 + c0) * 64 + l];
        bf16x8 b1 = B[(size_t)(t8 * 8 + c1) * 64 + l];
        acc0 = __builtin_amdgcn_mfma_f32_16x16x32_bf16(a, b0, acc0, 0, 0, 0);
        acc1 = __builtin_amdgcn_mfma_f32_16x16x32_bf16(a, b1, acc1, 0, 0, 0);
    }

    int fe0 = c0 * 16 + (l & 15);
    int fe1 = c1 * 16 + (l & 15);
    float bb0 = bias[fe0];
    float bb1 = bias[fe1];
#pragma unroll
    for (int r = 0; r < 4; ++r) {
        so[g * 4 + r][fe0] = acc0[r] + bb0;
        so[g * 4 + r][fe1] = acc1[r] + bb1;
    }
    __syncthreads();

    // per-node log_softmax: wave w handles nodes w*4 .. w*4+3
#pragma unroll
    for (int i = 0; i < 4; ++i) {
        int nd = w * 4 + i;
        float2 v = *(float2*)&so[nd][l * 2];
        float m = fmaxf(v.x, v.y);
#pragma unroll
        for (int off = 1; off < 64; off <<= 1)
            m = fmaxf(m, __shfl_xor(m, off));
        float s = expf(v.x - m) + expf(v.y - m);
#pragma unroll
        for (int off = 1; off < 64; off <<= 1)
            s += __shfl_xor(s, off);
        float ls = m + logf(s);
        float2 o;
        o.x = v.x - ls;
        o.y = v.y - ls;
        *(float2*)(out + (size_t)(base + nd) * C + l * 2) = o;
    }
}

extern "C" void kernel_launch(void* const* d_in, const int* in_sizes, int n_in,
                              void* d_out, int out_size, void* d_ws, size_t ws_size,
                              hipStream_t stream) {
    const float* x  = (const float*)d_in[0];
    const int*   ei = (const int*)d_in[1];
    const float* Wl = (const float*)d_in[2];
    const float* Wr = (const float*)d_in[3];
    const float* b  = (const float*)d_in[4];
    float* out = (float*)d_out;

    const int N = in_sizes[0] / C;   // 50000
    const int E = in_sizes[1] / 2;   // 600000

    // ws layout (16B-aligned pieces): ~28.5 MB total
    int* counts = (int*)d_ws;                             // N
    int* cursor = counts + N;                             // N
    int* csr    = cursor + N;                             // E
    unsigned short* xb   = (unsigned short*)(csr + E);    // N*C bf16
    unsigned short* aggb = xb + (size_t)N * C;            // N*C bf16
    unsigned short* wp   = aggb + (size_t)N * C;          // 256*128 bf16 pack

    hipMemsetAsync(counts, 0, (size_t)N * sizeof(int), stream);

    int eb4 = (E + 1023) / 1024;
    int XB = (N * C / 4) / 256;      // 6250 blocks for x conversion
    sage_count<<<eb4, 256, 0, stream>>>(ei, counts, E);
    sage_scan<<<1, 1024, 0, stream>>>(counts, cursor, N);
    sage_fill<<<eb4, 256, 0, stream>>>(ei, cursor, csr, E);
    sage_conv<<<XB + 16, 256, 0, stream>>>(x, Wl, Wr, xb, wp, XB);
    sage_agg<<<(N + 3) / 4, 256, 0, stream>>>(x, cursor, csr, aggb, N);
    sage_mfma_lsm<<<N / 16, 256, 0, stream>>>(xb, aggb, wp, b, out, N);
}

// Round 6
// 145.336 us; speedup vs baseline: 12.0397x; 1.1373x over previous
//
#include <hip/hip_runtime.h>
#include <cmath>

#define C 128     // in/out channels

typedef __bf16 bf16x8 __attribute__((ext_vector_type(8)));
typedef float  f32x4  __attribute__((ext_vector_type(4)));
typedef unsigned short u16x8 __attribute__((ext_vector_type(8)));

// fp32 -> bf16 bits, round-to-nearest-even
static __device__ __forceinline__ unsigned short f2b(float f) {
    unsigned int u = __builtin_bit_cast(unsigned int, f);
    u += 0x7FFFu + ((u >> 16) & 1u);
    return (unsigned short)(u >> 16);
}
// bf16 bits -> fp32
static __device__ __forceinline__ float b2f(unsigned short u) {
    return __builtin_bit_cast(float, (unsigned int)u << 16);
}

// ---------------------------------------------------------------------------
// Fused prep kernel, role by block range:
//  [0, CB)          : in-degree counts, 8 edges/thread (int atomics)
//  [CB, CB+XB)      : x fp32 -> bf16, 8 elems/thread
//  [CB+XB, +16)     : pack B = [Wl;Wr] (K=256 x N=128) into MFMA-fragment
//                     order: frag f = t*8+c, lane l, elem j:
//                       k = t*32 + (l>>4)*8 + j, n = c*16 + (l&15)
// ---------------------------------------------------------------------------
__global__ __launch_bounds__(256)
void sage_prep(const int* __restrict__ ei, const float* __restrict__ x,
               const float* __restrict__ Wl, const float* __restrict__ Wr,
               int* __restrict__ counts, unsigned short* __restrict__ xb,
               unsigned short* __restrict__ wp, int E, int CB, int XB) {
    int bid = blockIdx.x;
    int t = threadIdx.x;
    if (bid < CB) {
        int e = (bid * 256 + t) * 8;
        if (e + 7 < E) {
            int4 d0 = *(const int4*)(ei + E + e);
            int4 d1 = *(const int4*)(ei + E + e + 4);
            atomicAdd(&counts[d0.x], 1);
            atomicAdd(&counts[d0.y], 1);
            atomicAdd(&counts[d0.z], 1);
            atomicAdd(&counts[d0.w], 1);
            atomicAdd(&counts[d1.x], 1);
            atomicAdd(&counts[d1.y], 1);
            atomicAdd(&counts[d1.z], 1);
            atomicAdd(&counts[d1.w], 1);
        } else {
            for (; e < E; ++e) atomicAdd(&counts[ei[E + e]], 1);
        }
    } else if (bid < CB + XB) {
        int i = (bid - CB) * 256 + t;        // < N*C/8
        const float4* xp = (const float4*)x + (size_t)i * 2;
        float4 v0 = xp[0];
        float4 v1 = xp[1];
        u16x8 o;
        o[0] = f2b(v0.x); o[1] = f2b(v0.y); o[2] = f2b(v0.z); o[3] = f2b(v0.w);
        o[4] = f2b(v1.x); o[5] = f2b(v1.y); o[6] = f2b(v1.z); o[7] = f2b(v1.w);
        *(u16x8*)(xb + (size_t)i * 8) = o;
    } else {
        int s = (bid - CB - XB) * 256 + t;   // 0..4095
        int f = s >> 6, l = s & 63;
        int tt = f >> 3, c = f & 7;
        int g = l >> 4;
        int n = c * 16 + (l & 15);
        u16x8 o;
#pragma unroll
        for (int j = 0; j < 8; ++j) {
            int k = tt * 32 + g * 8 + j;
            float v = (k < C) ? Wl[(size_t)n * C + k] : Wr[(size_t)n * C + (k - C)];
            o[j] = f2b(v);
        }
        *(u16x8*)(wp + (size_t)s * 8) = o;
    }
}

// ---------------------------------------------------------------------------
// CSR build, step 2: single-block exclusive scan -> cursor.
// After sage_fill, cursor[i] == inclusive scan (end offset of node i).
// ---------------------------------------------------------------------------
__global__ __launch_bounds__(1024)
void sage_scan(const int* __restrict__ counts, int* __restrict__ cursor, int N) {
    __shared__ int part[1024];
    const int t = threadIdx.x;
    const int CH = 64;                    // 1024 * 64 = 65536 >= N
    const int lo = t * CH;

    int s = 0;
    if (lo + CH <= N) {
        const int4* c4 = (const int4*)(counts + lo);
#pragma unroll
        for (int i = 0; i < CH / 4; ++i) {
            int4 v = c4[i];
            s += v.x + v.y + v.z + v.w;
        }
    } else {
        for (int i = lo; i < N; ++i) s += counts[i];
    }
    part[t] = s;
    __syncthreads();
    for (int off = 1; off < 1024; off <<= 1) {
        int v = (t >= off) ? part[t - off] : 0;
        __syncthreads();
        part[t] += v;
        __syncthreads();
    }
    int run = (t == 0) ? 0 : part[t - 1];

    if (lo + CH <= N) {
        const int4* c4 = (const int4*)(counts + lo);
        int4* u4 = (int4*)(cursor + lo);
#pragma unroll
        for (int i = 0; i < CH / 4; ++i) {
            int4 v = c4[i];
            int4 o;
            o.x = run; run += v.x;
            o.y = run; run += v.y;
            o.z = run; run += v.z;
            o.w = run; run += v.w;
            u4[i] = o;
        }
    } else {
        for (int i = lo; i < N; ++i) {
            cursor[i] = run;
            run += counts[i];
        }
    }
}

// ---------------------------------------------------------------------------
// CSR build, step 3: scatter src ids; cursor becomes inclusive scan.
// ---------------------------------------------------------------------------
__global__ __launch_bounds__(256)
void sage_fill(const int* __restrict__ ei, int* __restrict__ cursor,
               int* __restrict__ csr, int E) {
    int i = blockIdx.x * blockDim.x + threadIdx.x;
    int e = i * 4;
    if (e + 3 < E) {
        int4 sv = *(const int4*)(ei + e);
        int4 dv = *(const int4*)(ei + E + e);
        csr[atomicAdd(&cursor[dv.x], 1)] = sv.x;
        csr[atomicAdd(&cursor[dv.y], 1)] = sv.y;
        csr[atomicAdd(&cursor[dv.z], 1)] = sv.z;
        csr[atomicAdd(&cursor[dv.w], 1)] = sv.w;
    } else {
        for (; e < E; ++e) {
            int pos = atomicAdd(&cursor[ei[E + e]], 1);
            csr[pos] = ei[e];
        }
    }
}

// ---------------------------------------------------------------------------
// Aggregation from bf16 xb: one wave per node, quarter-wave per neighbor row.
// 16 lanes x 16 B (dwordx4) = one 256 B bf16 row; 4 rows per wave-issue,
// 2-deep unroll (8 rows in flight). fp32 accumulate; cross-quarter reduce by
// two shfl_xor; quarter 0 writes the bf16 mean row.
// ---------------------------------------------------------------------------
__global__ __launch_bounds__(256)
void sage_agg(const unsigned short* __restrict__ xb,
              const int* __restrict__ cursor, const int* __restrict__ csr,
              unsigned short* __restrict__ aggb, int N) {
    int wv = threadIdx.x >> 6;
    int node = blockIdx.x * 4 + wv;
    if (node >= N) return;
    int ln = threadIdx.x & 63;
    int q = ln >> 4;        // quarter id: owns neighbor residues q (mod 4)
    int fl = ln & 15;       // ushort8 slot within the row

    int p0 = (node == 0) ? 0 : cursor[node - 1];
    int p1 = cursor[node];

    float a[8];
#pragma unroll
    for (int j = 0; j < 8; ++j) a[j] = 0.f;

    int p = p0 + q;
    for (; p + 4 < p1; p += 8) {
        int s0 = csr[p];
        int s1 = csr[p + 4];
        u16x8 v0 = *(const u16x8*)(xb + (size_t)s0 * C + fl * 8);
        u16x8 v1 = *(const u16x8*)(xb + (size_t)s1 * C + fl * 8);
#pragma unroll
        for (int j = 0; j < 8; ++j) a[j] += b2f(v0[j]);
#pragma unroll
        for (int j = 0; j < 8; ++j) a[j] += b2f(v1[j]);
    }
    if (p < p1) {
        int s0 = csr[p];
        u16x8 v0 = *(const u16x8*)(xb + (size_t)s0 * C + fl * 8);
#pragma unroll
        for (int j = 0; j < 8; ++j) a[j] += b2f(v0[j]);
    }

#pragma unroll
    for (int j = 0; j < 8; ++j) {
        a[j] += __shfl_xor(a[j], 16);
        a[j] += __shfl_xor(a[j], 32);
    }

    if (q == 0) {
        float inv = 1.0f / fmaxf((float)(p1 - p0), 1.0f);
        u16x8 o;
#pragma unroll
        for (int j = 0; j < 8; ++j) o[j] = f2b(a[j] * inv);
        *(u16x8*)(aggb + (size_t)node * C + fl * 8) = o;
    }
}

// ---------------------------------------------------------------------------
// MFMA GEMM + log_softmax. Block = 256 thr = 4 waves = 16 nodes x 128 feats.
// K = 256 ([agg | x]). Wave w owns n-tiles {2w, 2w+1}; 16 mfma/wave.
// A-frag (lane l): node = base + (l&15), k = t*32 + (l>>4)*8 + j  (16B load).
// B-frag: pre-packed wp, one coalesced 16B/lane load.
// D (verified m89): col(feat-in-tile) = l&15, row(node-in-tile) = (l>>4)*4+reg.
// Epilogue via 8.4 KB LDS; per-node softmax within one wave.
// ---------------------------------------------------------------------------
__global__ __launch_bounds__(256)
void sage_mfma_lsm(const unsigned short* __restrict__ xb,
                   const unsigned short* __restrict__ aggb,
                   const unsigned short* __restrict__ wp,
                   const float* __restrict__ bias,
                   float* __restrict__ out, int N) {
    __shared__ float so[16][132];   // +4 pad

    int t = threadIdx.x;
    int w = t >> 6, l = t & 63;
    int base = blockIdx.x * 16;
    int g = l >> 4;
    int node = base + (l & 15);

    const bf16x8* Aa = (const bf16x8*)(aggb + (size_t)node * C);
    const bf16x8* Ax = (const bf16x8*)(xb   + (size_t)node * C);
    const bf16x8* B  = (const bf16x8*)wp;

    int c0 = w * 2, c1 = w * 2 + 1;
    f32x4 acc0 = {0.f, 0.f, 0.f, 0.f};
    f32x4 acc1 = {0.f, 0.f, 0.f, 0.f};

#pragma unroll
    for (int t8 = 0; t8 < 8; ++t8) {
        bf16x8 a = (t8 < 4) ? Aa[t8 * 4 + g] : Ax[(t8 - 4) * 4 + g];
        bf16x8 b0 = B[(size_t)(t8 * 8 + c0) * 64 + l];
        bf16x8 b1 = B[(size_t)(t8 * 8 + c1) * 64 + l];
        acc0 = __builtin_amdgcn_mfma_f32_16x16x32_bf16(a, b0, acc0, 0, 0, 0);
        acc1 = __builtin_amdgcn_mfma_f32_16x16x32_bf16(a, b1, acc1, 0, 0, 0);
    }

    int fe0 = c0 * 16 + (l & 15);
    int fe1 = c1 * 16 + (l & 15);
    float bb0 = bias[fe0];
    float bb1 = bias[fe1];
#pragma unroll
    for (int r = 0; r < 4; ++r) {
        so[g * 4 + r][fe0] = acc0[r] + bb0;
        so[g * 4 + r][fe1] = acc1[r] + bb1;
    }
    __syncthreads();

    // per-node log_softmax: wave w handles nodes w*4 .. w*4+3
#pragma unroll
    for (int i = 0; i < 4; ++i) {
        int nd = w * 4 + i;
        float2 v = *(float2*)&so[nd][l * 2];
        float m = fmaxf(v.x, v.y);
#pragma unroll
        for (int off = 1; off < 64; off <<= 1)
            m = fmaxf(m, __shfl_xor(m, off));
        float s = expf(v.x - m) + expf(v.y - m);
#pragma unroll
        for (int off = 1; off < 64; off <<= 1)
            s += __shfl_xor(s, off);
        float ls = m + logf(s);
        float2 o;
        o.x = v.x - ls;
        o.y = v.y - ls;
        *(float2*)(out + (size_t)(base + nd) * C + l * 2) = o;
    }
}

extern "C" void kernel_launch(void* const* d_in, const int* in_sizes, int n_in,
                              void* d_out, int out_size, void* d_ws, size_t ws_size,
                              hipStream_t stream) {
    const float* x  = (const float*)d_in[0];
    const int*   ei = (const int*)d_in[1];
    const float* Wl = (const float*)d_in[2];
    const float* Wr = (const float*)d_in[3];
    const float* b  = (const float*)d_in[4];
    float* out = (float*)d_out;

    const int N = in_sizes[0] / C;   // 50000
    const int E = in_sizes[1] / 2;   // 600000

    // ws layout (16B-aligned pieces): ~28.5 MB total
    int* counts = (int*)d_ws;                             // N
    int* cursor = counts + N;                             // N
    int* csr    = cursor + N;                             // E
    unsigned short* xb   = (unsigned short*)(csr + E);    // N*C bf16
    unsigned short* aggb = xb + (size_t)N * C;            // N*C bf16
    unsigned short* wp   = aggb + (size_t)N * C;          // 256*128 bf16 pack

    hipMemsetAsync(counts, 0, (size_t)N * sizeof(int), stream);

    const int CB = (E + 2047) / 2048;        // count blocks (8 edges/thread)
    const int XB = (N * C / 8) / 256;        // 3125 conv blocks (8 elems/thread)
    int eb4 = (E + 1023) / 1024;

    sage_prep<<<CB + XB + 16, 256, 0, stream>>>(ei, x, Wl, Wr, counts, xb, wp,
                                                E, CB, XB);
    sage_scan<<<1, 1024, 0, stream>>>(counts, cursor, N);
    sage_fill<<<eb4, 256, 0, stream>>>(ei, cursor, csr, E);
    sage_agg<<<(N + 3) / 4, 256, 0, stream>>>(xb, cursor, csr, aggb, N);
    sage_mfma_lsm<<<N / 16, 256, 0, stream>>>(xb, aggb, wp, b, out, N);
}

// Round 7
// 144.686 us; speedup vs baseline: 12.0938x; 1.0045x over previous
//
#include <hip/hip_runtime.h>
#include <cmath>

#define C 128     // in/out channels

typedef __bf16 bf16x8 __attribute__((ext_vector_type(8)));
typedef float  f32x4  __attribute__((ext_vector_type(4)));
typedef unsigned short u16x8 __attribute__((ext_vector_type(8)));

// fp32 -> bf16 bits, round-to-nearest-even
static __device__ __forceinline__ unsigned short f2b(float f) {
    unsigned int u = __builtin_bit_cast(unsigned int, f);
    u += 0x7FFFu + ((u >> 16) & 1u);
    return (unsigned short)(u >> 16);
}
// bf16 bits -> fp32
static __device__ __forceinline__ float b2f(unsigned short u) {
    return __builtin_bit_cast(float, (unsigned int)u << 16);
}

// ---------------------------------------------------------------------------
// Zero the counts array (replaces hipMemsetAsync, whose fill kernel was
// measured at 43 us for 200 KB — pure launch/latency overhead).
// ---------------------------------------------------------------------------
__global__ __launch_bounds__(256)
void sage_zero(int4* __restrict__ p, int n4) {
    int i = blockIdx.x * blockDim.x + threadIdx.x;
    if (i < n4) p[i] = make_int4(0, 0, 0, 0);
}

// ---------------------------------------------------------------------------
// Fused prep kernel, role by block range:
//  [0, CB)          : in-degree counts, 8 edges/thread (int atomics)
//  [CB, CB+XB)      : x fp32 -> bf16, 8 elems/thread
//  [CB+XB, +16)     : pack B = [Wl;Wr] (K=256 x N=128) into MFMA-fragment
//                     order: frag f = t*8+c, lane l, elem j:
//                       k = t*32 + (l>>4)*8 + j, n = c*16 + (l&15)
// ---------------------------------------------------------------------------
__global__ __launch_bounds__(256)
void sage_prep(const int* __restrict__ ei, const float* __restrict__ x,
               const float* __restrict__ Wl, const float* __restrict__ Wr,
               int* __restrict__ counts, unsigned short* __restrict__ xb,
               unsigned short* __restrict__ wp, int E, int CB, int XB) {
    int bid = blockIdx.x;
    int t = threadIdx.x;
    if (bid < CB) {
        int e = (bid * 256 + t) * 8;
        if (e + 7 < E) {
            int4 d0 = *(const int4*)(ei + E + e);
            int4 d1 = *(const int4*)(ei + E + e + 4);
            atomicAdd(&counts[d0.x], 1);
            atomicAdd(&counts[d0.y], 1);
            atomicAdd(&counts[d0.z], 1);
            atomicAdd(&counts[d0.w], 1);
            atomicAdd(&counts[d1.x], 1);
            atomicAdd(&counts[d1.y], 1);
            atomicAdd(&counts[d1.z], 1);
            atomicAdd(&counts[d1.w], 1);
        } else {
            for (; e < E; ++e) atomicAdd(&counts[ei[E + e]], 1);
        }
    } else if (bid < CB + XB) {
        int i = (bid - CB) * 256 + t;        // < N*C/8
        const float4* xp = (const float4*)x + (size_t)i * 2;
        float4 v0 = xp[0];
        float4 v1 = xp[1];
        u16x8 o;
        o[0] = f2b(v0.x); o[1] = f2b(v0.y); o[2] = f2b(v0.z); o[3] = f2b(v0.w);
        o[4] = f2b(v1.x); o[5] = f2b(v1.y); o[6] = f2b(v1.z); o[7] = f2b(v1.w);
        *(u16x8*)(xb + (size_t)i * 8) = o;
    } else {
        int s = (bid - CB - XB) * 256 + t;   // 0..4095
        int f = s >> 6, l = s & 63;
        int tt = f >> 3, c = f & 7;
        int g = l >> 4;
        int n = c * 16 + (l & 15);
        u16x8 o;
#pragma unroll
        for (int j = 0; j < 8; ++j) {
            int k = tt * 32 + g * 8 + j;
            float v = (k < C) ? Wl[(size_t)n * C + k] : Wr[(size_t)n * C + (k - C)];
            o[j] = f2b(v);
        }
        *(u16x8*)(wp + (size_t)s * 8) = o;
    }
}

// ---------------------------------------------------------------------------
// CSR build, step 2: single-block exclusive scan -> cursor.
// After sage_fill, cursor[i] == inclusive scan (end offset of node i).
// ---------------------------------------------------------------------------
__global__ __launch_bounds__(1024)
void sage_scan(const int* __restrict__ counts, int* __restrict__ cursor, int N) {
    __shared__ int part[1024];
    const int t = threadIdx.x;
    const int CH = 64;                    // 1024 * 64 = 65536 >= N
    const int lo = t * CH;

    int s = 0;
    if (lo + CH <= N) {
        const int4* c4 = (const int4*)(counts + lo);
#pragma unroll
        for (int i = 0; i < CH / 4; ++i) {
            int4 v = c4[i];
            s += v.x + v.y + v.z + v.w;
        }
    } else {
        for (int i = lo; i < N; ++i) s += counts[i];
    }
    part[t] = s;
    __syncthreads();
    for (int off = 1; off < 1024; off <<= 1) {
        int v = (t >= off) ? part[t - off] : 0;
        __syncthreads();
        part[t] += v;
        __syncthreads();
    }
    int run = (t == 0) ? 0 : part[t - 1];

    if (lo + CH <= N) {
        const int4* c4 = (const int4*)(counts + lo);
        int4* u4 = (int4*)(cursor + lo);
#pragma unroll
        for (int i = 0; i < CH / 4; ++i) {
            int4 v = c4[i];
            int4 o;
            o.x = run; run += v.x;
            o.y = run; run += v.y;
            o.z = run; run += v.z;
            o.w = run; run += v.w;
            u4[i] = o;
        }
    } else {
        for (int i = lo; i < N; ++i) {
            cursor[i] = run;
            run += counts[i];
        }
    }
}

// ---------------------------------------------------------------------------
// CSR build, step 3: scatter src ids; cursor becomes inclusive scan.
// ---------------------------------------------------------------------------
__global__ __launch_bounds__(256)
void sage_fill(const int* __restrict__ ei, int* __restrict__ cursor,
               int* __restrict__ csr, int E) {
    int i = blockIdx.x * blockDim.x + threadIdx.x;
    int e = i * 4;
    if (e + 3 < E) {
        int4 sv = *(const int4*)(ei + e);
        int4 dv = *(const int4*)(ei + E + e);
        csr[atomicAdd(&cursor[dv.x], 1)] = sv.x;
        csr[atomicAdd(&cursor[dv.y], 1)] = sv.y;
        csr[atomicAdd(&cursor[dv.z], 1)] = sv.z;
        csr[atomicAdd(&cursor[dv.w], 1)] = sv.w;
    } else {
        for (; e < E; ++e) {
            int pos = atomicAdd(&cursor[ei[E + e]], 1);
            csr[pos] = ei[e];
        }
    }
}

// ---------------------------------------------------------------------------
// Aggregation from bf16 xb: one wave per node, quarter-wave per neighbor row.
// 16 lanes x 16 B (dwordx4) = one 256 B bf16 row; 2-deep unroll (8 rows in
// flight per wave). fp32 accumulate; cross-quarter reduce by two shfl_xor;
// quarter 0 writes the bf16 mean row.
// ---------------------------------------------------------------------------
__global__ __launch_bounds__(256)
void sage_agg(const unsigned short* __restrict__ xb,
              const int* __restrict__ cursor, const int* __restrict__ csr,
              unsigned short* __restrict__ aggb, int N) {
    int wv = threadIdx.x >> 6;
    int node = blockIdx.x * 4 + wv;
    if (node >= N) return;
    int ln = threadIdx.x & 63;
    int q = ln >> 4;        // quarter id: owns neighbor residues q (mod 4)
    int fl = ln & 15;       // ushort8 slot within the row

    int p0 = (node == 0) ? 0 : cursor[node - 1];
    int p1 = cursor[node];

    float a[8];
#pragma unroll
    for (int j = 0; j < 8; ++j) a[j] = 0.f;

    int p = p0 + q;
    for (; p + 4 < p1; p += 8) {
        int s0 = csr[p];
        int s1 = csr[p + 4];
        u16x8 v0 = *(const u16x8*)(xb + (size_t)s0 * C + fl * 8);
        u16x8 v1 = *(const u16x8*)(xb + (size_t)s1 * C + fl * 8);
#pragma unroll
        for (int j = 0; j < 8; ++j) a[j] += b2f(v0[j]);
#pragma unroll
        for (int j = 0; j < 8; ++j) a[j] += b2f(v1[j]);
    }
    if (p < p1) {
        int s0 = csr[p];
        u16x8 v0 = *(const u16x8*)(xb + (size_t)s0 * C + fl * 8);
#pragma unroll
        for (int j = 0; j < 8; ++j) a[j] += b2f(v0[j]);
    }

#pragma unroll
    for (int j = 0; j < 8; ++j) {
        a[j] += __shfl_xor(a[j], 16);
        a[j] += __shfl_xor(a[j], 32);
    }

    if (q == 0) {
        float inv = 1.0f / fmaxf((float)(p1 - p0), 1.0f);
        u16x8 o;
#pragma unroll
        for (int j = 0; j < 8; ++j) o[j] = f2b(a[j] * inv);
        *(u16x8*)(aggb + (size_t)node * C + fl * 8) = o;
    }
}

// ---------------------------------------------------------------------------
// MFMA GEMM + log_softmax. Block = 256 thr = 4 waves = 16 nodes x 128 feats.
// K = 256 ([agg | x]). Wave w owns n-tiles {2w, 2w+1}; 16 mfma/wave.
// A-frag (lane l): node = base + (l&15), k = t*32 + (l>>4)*8 + j  (16B load).
// B-frag: pre-packed wp, one coalesced 16B/lane load.
// D (verified m89): col(feat-in-tile) = l&15, row(node-in-tile) = (l>>4)*4+reg.
// Epilogue via 8.4 KB LDS; per-node softmax within one wave.
// ---------------------------------------------------------------------------
__global__ __launch_bounds__(256)
void sage_mfma_lsm(const unsigned short* __restrict__ xb,
                   const unsigned short* __restrict__ aggb,
                   const unsigned short* __restrict__ wp,
                   const float* __restrict__ bias,
                   float* __restrict__ out, int N) {
    __shared__ float so[16][132];   // +4 pad

    int t = threadIdx.x;
    int w = t >> 6, l = t & 63;
    int base = blockIdx.x * 16;
    int g = l >> 4;
    int node = base + (l & 15);

    const bf16x8* Aa = (const bf16x8*)(aggb + (size_t)node * C);
    const bf16x8* Ax = (const bf16x8*)(xb   + (size_t)node * C);
    const bf16x8* B  = (const bf16x8*)wp;

    int c0 = w * 2, c1 = w * 2 + 1;
    f32x4 acc0 = {0.f, 0.f, 0.f, 0.f};
    f32x4 acc1 = {0.f, 0.f, 0.f, 0.f};

#pragma unroll
    for (int t8 = 0; t8 < 8; ++t8) {
        bf16x8 a = (t8 < 4) ? Aa[t8 * 4 + g] : Ax[(t8 - 4) * 4 + g];
        bf16x8 b0 = B[(size_t)(t8 * 8 + c0) * 64 + l];
        bf16x8 b1 = B[(size_t)(t8 * 8 + c1) * 64 + l];
        acc0 = __builtin_amdgcn_mfma_f32_16x16x32_bf16(a, b0, acc0, 0, 0, 0);
        acc1 = __builtin_amdgcn_mfma_f32_16x16x32_bf16(a, b1, acc1, 0, 0, 0);
    }

    int fe0 = c0 * 16 + (l & 15);
    int fe1 = c1 * 16 + (l & 15);
    float bb0 = bias[fe0];
    float bb1 = bias[fe1];
#pragma unroll
    for (int r = 0; r < 4; ++r) {
        so[g * 4 + r][fe0] = acc0[r] + bb0;
        so[g * 4 + r][fe1] = acc1[r] + bb1;
    }
    __syncthreads();

    // per-node log_softmax: wave w handles nodes w*4 .. w*4+3
#pragma unroll
    for (int i = 0; i < 4; ++i) {
        int nd = w * 4 + i;
        float2 v = *(float2*)&so[nd][l * 2];
        float m = fmaxf(v.x, v.y);
#pragma unroll
        for (int off = 1; off < 64; off <<= 1)
            m = fmaxf(m, __shfl_xor(m, off));
        float s = expf(v.x - m) + expf(v.y - m);
#pragma unroll
        for (int off = 1; off < 64; off <<= 1)
            s += __shfl_xor(s, off);
        float ls = m + logf(s);
        float2 o;
        o.x = v.x - ls;
        o.y = v.y - ls;
        *(float2*)(out + (size_t)(base + nd) * C + l * 2) = o;
    }
}

extern "C" void kernel_launch(void* const* d_in, const int* in_sizes, int n_in,
                              void* d_out, int out_size, void* d_ws, size_t ws_size,
                              hipStream_t stream) {
    const float* x  = (const float*)d_in[0];
    const int*   ei = (const int*)d_in[1];
    const float* Wl = (const float*)d_in[2];
    const float* Wr = (const float*)d_in[3];
    const float* b  = (const float*)d_in[4];
    float* out = (float*)d_out;

    const int N = in_sizes[0] / C;   // 50000
    const int E = in_sizes[1] / 2;   // 600000

    // ws layout (16B-aligned pieces): ~28.5 MB total
    int* counts = (int*)d_ws;                             // N
    int* cursor = counts + N;                             // N
    int* csr    = cursor + N;                             // E
    unsigned short* xb   = (unsigned short*)(csr + E);    // N*C bf16
    unsigned short* aggb = xb + (size_t)N * C;            // N*C bf16
    unsigned short* wp   = aggb + (size_t)N * C;          // 256*128 bf16 pack

    const int CB = (E + 2047) / 2048;        // count blocks (8 edges/thread)
    const int XB = (N * C / 8) / 256;        // 3125 conv blocks (8 elems/thread)
    int eb4 = (E + 1023) / 1024;
    int n4 = (N + 3) / 4;                    // int4 count for zeroing

    sage_zero<<<(n4 + 255) / 256, 256, 0, stream>>>((int4*)counts, n4);
    sage_prep<<<CB + XB + 16, 256, 0, stream>>>(ei, x, Wl, Wr, counts, xb, wp,
                                                E, CB, XB);
    sage_scan<<<1, 1024, 0, stream>>>(counts, cursor, N);
    sage_fill<<<eb4, 256, 0, stream>>>(ei, cursor, csr, E);
    sage_agg<<<(N + 3) / 4, 256, 0, stream>>>(xb, cursor, csr, aggb, N);
    sage_mfma_lsm<<<N / 16, 256, 0, stream>>>(xb, aggb, wp, b, out, N);
}